// Round 1
// baseline (247.119 us; speedup 1.0000x reference)
//
#include <hip/hip_runtime.h>
#include <stdint.h>

#define BB 2
#define HH 16
#define LL 2048
#define DD 1024

typedef __bf16 b16x8 __attribute__((ext_vector_type(8)));
typedef float f32x4 __attribute__((ext_vector_type(4)));

__device__ __forceinline__ short f2bf(float f) {
  unsigned u = __builtin_bit_cast(unsigned, f);
  return (short)((u + 0x7fffu + ((u >> 16) & 1u)) >> 16);
}

__device__ __forceinline__ void gl_lds16(const void* gp, void* lp) {
  __builtin_amdgcn_global_load_lds(
      (const __attribute__((address_space(1))) void*)gp,
      (__attribute__((address_space(3))) void*)lp, 16, 0, 0);
}

// ---------------- X f32 -> bf16 ----------------
__global__ __launch_bounds__(256) void xcvt(const float* __restrict__ X,
                                            short* __restrict__ Xb) {
  int i = blockIdx.x * 256 + threadIdx.x;
  float4 v = ((const float4*)X)[i];
  short4 o;
  o.x = f2bf(v.x); o.y = f2bf(v.y); o.z = f2bf(v.z); o.w = f2bf(v.w);
  ((short4*)Xb)[i] = o;
}

// ---------------- W[k][n] f32 -> Wt[n][k] bf16 (4 mats via blockIdx.z) ------
__global__ __launch_bounds__(256) void wtrans(const float* __restrict__ W0,
                                              const float* __restrict__ W1,
                                              const float* __restrict__ W2,
                                              const float* __restrict__ W3,
                                              short* __restrict__ Wt) {
  __shared__ float t[32][33];
  const float* W = blockIdx.z == 0 ? W0 : blockIdx.z == 1 ? W1
                 : blockIdx.z == 2 ? W2 : W3;
  short* dst = Wt + (size_t)blockIdx.z * DD * DD;
  int tx = threadIdx.x & 31, ty0 = threadIdx.x >> 5;
  int nb = blockIdx.x * 32, kb = blockIdx.y * 32;
#pragma unroll
  for (int i = 0; i < 4; ++i)
    t[ty0 + i * 8][tx] = W[(size_t)(kb + ty0 + i * 8) * DD + nb + tx];
  __syncthreads();
#pragma unroll
  for (int i = 0; i < 4; ++i)
    dst[(size_t)(nb + ty0 + i * 8) * DD + kb + tx] = f2bf(t[tx][ty0 + i * 8]);
}

// ---------------- fused QKV GEMM: [4096,1024] @ Wt -> Q,K,Vt ---------------
// grid (24, 32): blockIdx.x*128 = global n in [0,3072); sel = which weight.
__global__ __launch_bounds__(256) void qkv_gemm(const short* __restrict__ Xb,
                                                const short* __restrict__ Wall,
                                                const float* __restrict__ bQ,
                                                const float* __restrict__ bK,
                                                const float* __restrict__ bV,
                                                short* __restrict__ Qo,
                                                short* __restrict__ Ko,
                                                short* __restrict__ Vto) {
  __shared__ __align__(16) short As[128 * 32];
  __shared__ __align__(16) short Bs[128 * 32];

  const int tid = threadIdx.x;
  const int lane = tid & 63;
  const int wid = tid >> 6;
  const int m0 = blockIdx.y * 128;
  const int ng = blockIdx.x * 128;
  const int sel = ng >> 10;
  const int n0 = ng & 1023;
  const short* W = Wall + (size_t)sel * DD * DD;

  const int wrow = wid >> 1, wcol = wid & 1;
  const int lrow = lane & 15;
  const int lk8 = (lane >> 4) * 8;
  const int srow = lane >> 2;       // staging: row within 16-row chunk
  const int scol = (lane & 3) * 8;  // staging: k element offset

  f32x4 z4 = {0.f, 0.f, 0.f, 0.f};
  f32x4 acc[4][4];
#pragma unroll
  for (int i = 0; i < 4; ++i)
#pragma unroll
    for (int j = 0; j < 4; ++j) acc[i][j] = z4;

  for (int kt = 0; kt < DD; kt += 32) {
#pragma unroll
    for (int i = 0; i < 2; ++i) {
      int c = wid * 2 + i;
      gl_lds16(Xb + (size_t)(m0 + c * 16 + srow) * DD + kt + scol, As + c * 512);
      gl_lds16(W + (size_t)(n0 + c * 16 + srow) * DD + kt + scol, Bs + c * 512);
    }
    __syncthreads();
    b16x8 a[4], b[4];
#pragma unroll
    for (int i = 0; i < 4; ++i)
      a[i] = *(const b16x8*)(As + (wrow * 64 + i * 16 + lrow) * 32 + lk8);
#pragma unroll
    for (int j = 0; j < 4; ++j)
      b[j] = *(const b16x8*)(Bs + (wcol * 64 + j * 16 + lrow) * 32 + lk8);
#pragma unroll
    for (int i = 0; i < 4; ++i)
#pragma unroll
      for (int j = 0; j < 4; ++j)
        acc[i][j] = __builtin_amdgcn_mfma_f32_16x16x32_bf16(a[i], b[j], acc[i][j], 0, 0, 0);
    __syncthreads();
  }

  const float* bias = sel == 0 ? bQ : sel == 1 ? bK : bV;
  float bv[4];
#pragma unroll
  for (int j = 0; j < 4; ++j) bv[j] = bias[n0 + wcol * 64 + j * 16 + lrow];

  const int rbase = (lane >> 4) * 4;
  if (sel == 2) {
    // V: write transposed (B,H,DK,L) so attention PV reads are contiguous.
#pragma unroll
    for (int i = 0; i < 4; ++i) {
      int gm = m0 + wrow * 64 + i * 16 + rbase;
      int bb = gm >> 11, lb = gm & 2047;
#pragma unroll
      for (int j = 0; j < 4; ++j) {
        int gn = n0 + wcol * 64 + j * 16 + lrow;
        int h = gn >> 6, dk = gn & 63;
        short4 pk;
        pk.x = f2bf(acc[i][j][0] + bv[j]);
        pk.y = f2bf(acc[i][j][1] + bv[j]);
        pk.z = f2bf(acc[i][j][2] + bv[j]);
        pk.w = f2bf(acc[i][j][3] + bv[j]);
        *(short4*)(Vto + ((size_t)((bb * HH + h) * 64 + dk)) * LL + lb) = pk;
      }
    }
  } else {
    short* dst = sel == 0 ? Qo : Ko;
    float sc = sel == 0 ? 0.125f : 1.0f;  // fold 1/sqrt(64) into Q
#pragma unroll
    for (int i = 0; i < 4; ++i) {
      int gm = m0 + wrow * 64 + i * 16 + rbase;
#pragma unroll
      for (int j = 0; j < 4; ++j) {
        int gn = n0 + wcol * 64 + j * 16 + lrow;
        int h = gn >> 6, dk = gn & 63;
#pragma unroll
        for (int r = 0; r < 4; ++r) {
          int m = gm + r;
          int bb = m >> 11, lq = m & 2047;
          dst[((size_t)(bb * HH + h) * LL + lq) * 64 + dk] =
              f2bf((acc[i][j][r] + bv[j]) * sc);
        }
      }
    }
  }
}

// ---------------- flash attention ----------------
// grid (16, 32): 128 q-rows per block for one (b,h); 4 waves x 32 rows.
__global__ __launch_bounds__(256) void attn(const short* __restrict__ Qg,
                                            const short* __restrict__ Kg,
                                            const short* __restrict__ Vt,
                                            short* __restrict__ Og) {
  __shared__ __align__(16) short Ks[64 * 64];      // [key][d], swizzled rows
  __shared__ __align__(16) short Vs[64 * 64];      // [d][key], swizzled rows
  __shared__ __align__(16) short Ps[4 * 32 * 64];  // per-wave P, swizzled

  const int tid = threadIdx.x;
  const int lane = tid & 63;
  const int wid = tid >> 6;
  const int bh = blockIdx.y;
  const int q0 = blockIdx.x * 128;

  const short* Qb = Qg + (size_t)bh * LL * 64;
  const short* Kb = Kg + (size_t)bh * LL * 64;
  const short* Vb = Vt + (size_t)bh * 64 * LL;

  const int lrow = lane & 15;
  const int rbase = (lane >> 4) * 4;
  const int hi16 = (lane >> 4) * 16;
  const int r8 = lane >> 3;
  const int c8 = lane & 7;
  const int swz8 = (c8 ^ r8) * 8;  // pre-swizzled global source offset (elems)

  b16x8 qf[2][2];
#pragma unroll
  for (int f = 0; f < 2; ++f)
#pragma unroll
    for (int ks = 0; ks < 2; ++ks)
      qf[f][ks] = *(const b16x8*)(Qb + (size_t)(q0 + wid * 32 + f * 16 + lrow) * 64 +
                                  ks * 32 + (lane >> 4) * 8);

  f32x4 z4 = {0.f, 0.f, 0.f, 0.f};
  f32x4 accO[2][4];
  float m_i[2][4], l_i[2][4];
#pragma unroll
  for (int f = 0; f < 2; ++f) {
#pragma unroll
    for (int d = 0; d < 4; ++d) accO[f][d] = z4;
#pragma unroll
    for (int r = 0; r < 4; ++r) { m_i[f][r] = -1e30f; l_i[f][r] = 0.f; }
  }

  short* Pw = Ps + wid * 2048;

  for (int kt = 0; kt < LL / 64; ++kt) {
    // stage K (8 chunks) + V (8 chunks), 2+2 per wave, linear LDS dest,
    // inverse-swizzled global source.
#pragma unroll
    for (int i = 0; i < 2; ++i) {
      int c = wid * 2 + i;
      gl_lds16(Kb + (size_t)(kt * 64 + c * 8 + r8) * 64 + swz8, Ks + c * 512);
      gl_lds16(Vb + (size_t)(c * 8 + r8) * LL + kt * 64 + swz8, Vs + c * 512);
    }
    __syncthreads();

    // S = Q K^T  (Q pre-scaled by 0.125)
    f32x4 sacc[2][4];
#pragma unroll
    for (int f = 0; f < 2; ++f)
#pragma unroll
      for (int kf = 0; kf < 4; ++kf) sacc[f][kf] = z4;

#pragma unroll
    for (int kf = 0; kf < 4; ++kf) {
      int key = kf * 16 + lrow;
      int sw = (key & 7) << 4;
#pragma unroll
      for (int ks = 0; ks < 2; ++ks) {
        b16x8 kfr = *(const b16x8*)(Ks + key * 64 + (((ks * 64 + hi16) ^ sw) >> 1));
#pragma unroll
        for (int f = 0; f < 2; ++f)
          sacc[f][kf] =
              __builtin_amdgcn_mfma_f32_16x16x32_bf16(qf[f][ks], kfr, sacc[f][kf], 0, 0, 0);
      }
    }

    // online softmax (row = rbase+r within 16, cols spread over 16 lanes x 4 kf)
#pragma unroll
    for (int f = 0; f < 2; ++f) {
#pragma unroll
      for (int r = 0; r < 4; ++r) {
        float mx = fmaxf(fmaxf(sacc[f][0][r], sacc[f][1][r]),
                         fmaxf(sacc[f][2][r], sacc[f][3][r]));
        mx = fmaxf(mx, __shfl_xor(mx, 1));
        mx = fmaxf(mx, __shfl_xor(mx, 2));
        mx = fmaxf(mx, __shfl_xor(mx, 4));
        mx = fmaxf(mx, __shfl_xor(mx, 8));
        float mnew = fmaxf(m_i[f][r], mx);
        float corr = __expf(m_i[f][r] - mnew);
        int q32 = f * 16 + rbase + r;
        int swq = (q32 & 7) << 4;
        float ps = 0.f;
#pragma unroll
        for (int kf = 0; kf < 4; ++kf) {
          float p = __expf(sacc[f][kf][r] - mnew);
          ps += p;
          int key = kf * 16 + lrow;
          Pw[q32 * 64 + (((key * 2) ^ swq) >> 1)] = f2bf(p);
        }
        ps += __shfl_xor(ps, 1);
        ps += __shfl_xor(ps, 2);
        ps += __shfl_xor(ps, 4);
        ps += __shfl_xor(ps, 8);
        l_i[f][r] = l_i[f][r] * corr + ps;
        m_i[f][r] = mnew;
#pragma unroll
        for (int d = 0; d < 4; ++d) accO[f][d][r] *= corr;
      }
    }

    asm volatile("s_waitcnt lgkmcnt(0)" ::: "memory");

    // O += P V
    b16x8 pfr[2][2], vfr[4][2];
#pragma unroll
    for (int f = 0; f < 2; ++f)
#pragma unroll
      for (int ks = 0; ks < 2; ++ks) {
        int q32 = f * 16 + lrow;
        pfr[f][ks] = *(const b16x8*)(Pw + q32 * 64 +
                                     (((ks * 64 + hi16) ^ ((q32 & 7) << 4)) >> 1));
      }
#pragma unroll
    for (int d = 0; d < 4; ++d)
#pragma unroll
      for (int ks = 0; ks < 2; ++ks) {
        int dd = d * 16 + lrow;
        vfr[d][ks] = *(const b16x8*)(Vs + dd * 64 +
                                     (((ks * 64 + hi16) ^ ((dd & 7) << 4)) >> 1));
      }
#pragma unroll
    for (int f = 0; f < 2; ++f)
#pragma unroll
      for (int d = 0; d < 4; ++d)
#pragma unroll
        for (int ks = 0; ks < 2; ++ks)
          accO[f][d] =
              __builtin_amdgcn_mfma_f32_16x16x32_bf16(pfr[f][ks], vfr[d][ks], accO[f][d], 0, 0, 0);

    __syncthreads();
  }

  // epilogue: O /= l, write to (B, L, H*DK) bf16
  const int bb = bh >> 4, h = bh & 15;
#pragma unroll
  for (int f = 0; f < 2; ++f)
#pragma unroll
    for (int d = 0; d < 4; ++d)
#pragma unroll
      for (int r = 0; r < 4; ++r) {
        int q = q0 + wid * 32 + f * 16 + rbase + r;
        int col = h * 64 + d * 16 + lrow;
        float v = accO[f][d][r] / l_i[f][r];
        Og[(size_t)(bb * LL + q) * DD + col] = f2bf(v);
      }
}

// ---------------- output GEMM: attn[4096,1024] @ WOt + bO -> f32 ----------
__global__ __launch_bounds__(256) void out_gemm(const short* __restrict__ Ab,
                                                const short* __restrict__ Wt,
                                                const float* __restrict__ bO,
                                                float* __restrict__ Out) {
  __shared__ __align__(16) short As[128 * 32];
  __shared__ __align__(16) short Bs[128 * 32];

  const int tid = threadIdx.x;
  const int lane = tid & 63;
  const int wid = tid >> 6;
  const int m0 = blockIdx.y * 128;
  const int n0 = blockIdx.x * 128;

  const int wrow = wid >> 1, wcol = wid & 1;
  const int lrow = lane & 15;
  const int lk8 = (lane >> 4) * 8;
  const int srow = lane >> 2;
  const int scol = (lane & 3) * 8;

  f32x4 z4 = {0.f, 0.f, 0.f, 0.f};
  f32x4 acc[4][4];
#pragma unroll
  for (int i = 0; i < 4; ++i)
#pragma unroll
    for (int j = 0; j < 4; ++j) acc[i][j] = z4;

  for (int kt = 0; kt < DD; kt += 32) {
#pragma unroll
    for (int i = 0; i < 2; ++i) {
      int c = wid * 2 + i;
      gl_lds16(Ab + (size_t)(m0 + c * 16 + srow) * DD + kt + scol, As + c * 512);
      gl_lds16(Wt + (size_t)(n0 + c * 16 + srow) * DD + kt + scol, Bs + c * 512);
    }
    __syncthreads();
    b16x8 a[4], b[4];
#pragma unroll
    for (int i = 0; i < 4; ++i)
      a[i] = *(const b16x8*)(As + (wrow * 64 + i * 16 + lrow) * 32 + lk8);
#pragma unroll
    for (int j = 0; j < 4; ++j)
      b[j] = *(const b16x8*)(Bs + (wcol * 64 + j * 16 + lrow) * 32 + lk8);
#pragma unroll
    for (int i = 0; i < 4; ++i)
#pragma unroll
      for (int j = 0; j < 4; ++j)
        acc[i][j] = __builtin_amdgcn_mfma_f32_16x16x32_bf16(a[i], b[j], acc[i][j], 0, 0, 0);
    __syncthreads();
  }

  float bv[4];
#pragma unroll
  for (int j = 0; j < 4; ++j) bv[j] = bO[n0 + wcol * 64 + j * 16 + lrow];

  const int rbase = (lane >> 4) * 4;
#pragma unroll
  for (int i = 0; i < 4; ++i) {
    int gm = m0 + wrow * 64 + i * 16 + rbase;
#pragma unroll
    for (int j = 0; j < 4; ++j) {
      int gn = n0 + wcol * 64 + j * 16 + lrow;
#pragma unroll
      for (int r = 0; r < 4; ++r)
        Out[(size_t)(gm + r) * DD + gn] = acc[i][j][r] + bv[j];
    }
  }
}

extern "C" void kernel_launch(void* const* d_in, const int* in_sizes, int n_in,
                              void* d_out, int out_size, void* d_ws, size_t ws_size,
                              hipStream_t stream) {
  const float* X = (const float*)d_in[0];
  const float* WQ = (const float*)d_in[1];
  const float* bQ = (const float*)d_in[2];
  const float* WK = (const float*)d_in[3];
  const float* bK = (const float*)d_in[4];
  const float* WV = (const float*)d_in[5];
  const float* bV = (const float*)d_in[6];
  const float* WO = (const float*)d_in[7];
  const float* bO = (const float*)d_in[8];
  float* Out = (float*)d_out;

  // workspace layout (shorts): Xb 4M | Wt 4x1M | Q 4M | K 4M | Vt 4M | At 4M
  if (ws_size < (size_t)24 * 1024 * 1024 * 2) return;
  short* ws = (short*)d_ws;
  short* Xb = ws;
  short* Wt = Xb + (size_t)4096 * 1024;
  short* Qb = Wt + (size_t)4 * 1024 * 1024;
  short* Kb = Qb + (size_t)4096 * 1024;
  short* Vtb = Kb + (size_t)4096 * 1024;
  short* At = Vtb + (size_t)4096 * 1024;

  hipLaunchKernelGGL(xcvt, dim3(4096), dim3(256), 0, stream, X, Xb);
  hipLaunchKernelGGL(wtrans, dim3(32, 32, 4), dim3(256), 0, stream, WQ, WK, WV, WO, Wt);
  hipLaunchKernelGGL(qkv_gemm, dim3(24, 32), dim3(256), 0, stream, Xb, Wt, bQ, bK, bV,
                     Qb, Kb, Vtb);
  hipLaunchKernelGGL(attn, dim3(16, 32), dim3(256), 0, stream, Qb, Kb, Vtb, At);
  hipLaunchKernelGGL(out_gemm, dim3(8, 32), dim3(256), 0, stream, At,
                     Wt + (size_t)3 * 1024 * 1024, bO, Out);
}

// Round 2
// 152.752 us; speedup vs baseline: 1.6178x; 1.6178x over previous
//
#include <hip/hip_runtime.h>
#include <stdint.h>

#define BB 2
#define HH 16
#define LL 2048
#define DD 1024

typedef __bf16 b16x8 __attribute__((ext_vector_type(8)));
typedef float f32x4 __attribute__((ext_vector_type(4)));

__device__ __forceinline__ short f2bf(float f) {
  unsigned u = __builtin_bit_cast(unsigned, f);
  return (short)((u + 0x7fffu + ((u >> 16) & 1u)) >> 16);
}

__device__ __forceinline__ void gl_lds16(const void* gp, void* lp) {
  __builtin_amdgcn_global_load_lds(
      (const __attribute__((address_space(1))) void*)gp,
      (__attribute__((address_space(3))) void*)lp, 16, 0, 0);
}

// ---------------- X f32 -> bf16 ----------------
__global__ __launch_bounds__(256) void xcvt(const float* __restrict__ X,
                                            short* __restrict__ Xb) {
  int i = blockIdx.x * 256 + threadIdx.x;
  float4 v = ((const float4*)X)[i];
  short4 o;
  o.x = f2bf(v.x); o.y = f2bf(v.y); o.z = f2bf(v.z); o.w = f2bf(v.w);
  ((short4*)Xb)[i] = o;
}

// ---------------- W[k][n] f32 -> Wt[n][k] bf16 (4 mats via blockIdx.z) ------
__global__ __launch_bounds__(256) void wtrans(const float* __restrict__ W0,
                                              const float* __restrict__ W1,
                                              const float* __restrict__ W2,
                                              const float* __restrict__ W3,
                                              short* __restrict__ Wt) {
  __shared__ float t[32][33];
  const float* W = blockIdx.z == 0 ? W0 : blockIdx.z == 1 ? W1
                 : blockIdx.z == 2 ? W2 : W3;
  short* dst = Wt + (size_t)blockIdx.z * DD * DD;
  int tx = threadIdx.x & 31, ty0 = threadIdx.x >> 5;
  int nb = blockIdx.x * 32, kb = blockIdx.y * 32;
#pragma unroll
  for (int i = 0; i < 4; ++i)
    t[ty0 + i * 8][tx] = W[(size_t)(kb + ty0 + i * 8) * DD + nb + tx];
  __syncthreads();
#pragma unroll
  for (int i = 0; i < 4; ++i)
    dst[(size_t)(nb + ty0 + i * 8) * DD + kb + tx] = f2bf(t[tx][ty0 + i * 8]);
}

// ---------------- fused QKV GEMM: [4096,1024] @ Wt -> Q,K,Vt ---------------
// grid (24, 32): blockIdx.x*128 = global n in [0,3072); sel = which weight.
__global__ __launch_bounds__(256) void qkv_gemm(const short* __restrict__ Xb,
                                                const short* __restrict__ Wall,
                                                const float* __restrict__ bQ,
                                                const float* __restrict__ bK,
                                                const float* __restrict__ bV,
                                                short* __restrict__ Qo,
                                                short* __restrict__ Ko,
                                                short* __restrict__ Vto) {
  __shared__ __align__(16) short As[128 * 32];
  __shared__ __align__(16) short Bs[128 * 32];

  const int tid = threadIdx.x;
  const int lane = tid & 63;
  const int wid = tid >> 6;
  const int m0 = blockIdx.y * 128;
  const int ng = blockIdx.x * 128;
  const int sel = ng >> 10;
  const int n0 = ng & 1023;
  const short* W = Wall + (size_t)sel * DD * DD;

  const int wrow = wid >> 1, wcol = wid & 1;
  const int lrow = lane & 15;
  const int lk8 = (lane >> 4) * 8;
  const int srow = lane >> 2;       // staging: row within 16-row chunk
  const int scol = (lane & 3) * 8;  // staging: k element offset

  f32x4 z4 = {0.f, 0.f, 0.f, 0.f};
  f32x4 acc[4][4];
#pragma unroll
  for (int i = 0; i < 4; ++i)
#pragma unroll
    for (int j = 0; j < 4; ++j) acc[i][j] = z4;

  for (int kt = 0; kt < DD; kt += 32) {
#pragma unroll
    for (int i = 0; i < 2; ++i) {
      int c = wid * 2 + i;
      gl_lds16(Xb + (size_t)(m0 + c * 16 + srow) * DD + kt + scol, As + c * 512);
      gl_lds16(W + (size_t)(n0 + c * 16 + srow) * DD + kt + scol, Bs + c * 512);
    }
    __syncthreads();
    b16x8 a[4], b[4];
#pragma unroll
    for (int i = 0; i < 4; ++i)
      a[i] = *(const b16x8*)(As + (wrow * 64 + i * 16 + lrow) * 32 + lk8);
#pragma unroll
    for (int j = 0; j < 4; ++j)
      b[j] = *(const b16x8*)(Bs + (wcol * 64 + j * 16 + lrow) * 32 + lk8);
#pragma unroll
    for (int i = 0; i < 4; ++i)
#pragma unroll
      for (int j = 0; j < 4; ++j)
        acc[i][j] = __builtin_amdgcn_mfma_f32_16x16x32_bf16(a[i], b[j], acc[i][j], 0, 0, 0);
    __syncthreads();
  }

  const float* bias = sel == 0 ? bQ : sel == 1 ? bK : bV;
  float bv[4];
#pragma unroll
  for (int j = 0; j < 4; ++j) bv[j] = bias[n0 + wcol * 64 + j * 16 + lrow];

  const int rbase = (lane >> 4) * 4;
  if (sel == 2) {
    // V: write transposed (B,H,DK,L) so attention PV reads are contiguous.
#pragma unroll
    for (int i = 0; i < 4; ++i) {
      int gm = m0 + wrow * 64 + i * 16 + rbase;
      int bb = gm >> 11, lb = gm & 2047;
#pragma unroll
      for (int j = 0; j < 4; ++j) {
        int gn = n0 + wcol * 64 + j * 16 + lrow;
        int h = gn >> 6, dk = gn & 63;
        short4 pk;
        pk.x = f2bf(acc[i][j][0] + bv[j]);
        pk.y = f2bf(acc[i][j][1] + bv[j]);
        pk.z = f2bf(acc[i][j][2] + bv[j]);
        pk.w = f2bf(acc[i][j][3] + bv[j]);
        *(short4*)(Vto + ((size_t)((bb * HH + h) * 64 + dk)) * LL + lb) = pk;
      }
    }
  } else {
    short* dst = sel == 0 ? Qo : Ko;
    // Q: fold 1/sqrt(64) AND log2(e) so softmax runs in exp2 domain.
    float sc = sel == 0 ? 0.18033688011112042f : 1.0f;
#pragma unroll
    for (int i = 0; i < 4; ++i) {
      int gm = m0 + wrow * 64 + i * 16 + rbase;
#pragma unroll
      for (int j = 0; j < 4; ++j) {
        int gn = n0 + wcol * 64 + j * 16 + lrow;
        int h = gn >> 6, dk = gn & 63;
#pragma unroll
        for (int r = 0; r < 4; ++r) {
          int m = gm + r;
          int bb = m >> 11, lq = m & 2047;
          dst[((size_t)(bb * HH + h) * LL + lq) * 64 + dk] =
              f2bf((acc[i][j][r] + bv[j]) * sc);
        }
      }
    }
  }
}

// ---------------- flash attention ----------------
// grid (16, 32): 128 q-rows per block for one (b,h); 4 waves x 32 rows.
// Double-buffered K/V prefetch; defer-max softmax (exp2 domain, THR=8);
// lane-partial l with single epilogue reduce.
__global__ __launch_bounds__(256) void attn(const short* __restrict__ Qg,
                                            const short* __restrict__ Kg,
                                            const short* __restrict__ Vt,
                                            short* __restrict__ Og) {
  __shared__ __align__(16) short Ks[2][64 * 64];   // [key][d], swizzled rows
  __shared__ __align__(16) short Vs[2][64 * 64];   // [d][key], swizzled rows
  __shared__ __align__(16) short Ps[4 * 32 * 64];  // per-wave P, swizzled

  const int tid = threadIdx.x;
  const int lane = tid & 63;
  const int wid = tid >> 6;
  const int bh = blockIdx.y;
  const int q0 = blockIdx.x * 128;

  const short* Qb = Qg + (size_t)bh * LL * 64;
  const short* Kb = Kg + (size_t)bh * LL * 64;
  const short* Vb = Vt + (size_t)bh * 64 * LL;

  const int lrow = lane & 15;
  const int rbase = (lane >> 4) * 4;
  const int hi16 = (lane >> 4) * 16;
  const int r8 = lane >> 3;
  const int c8 = lane & 7;
  const int swz8 = (c8 ^ r8) * 8;  // pre-swizzled global source offset (elems)

  b16x8 qf[2][2];
#pragma unroll
  for (int f = 0; f < 2; ++f)
#pragma unroll
    for (int ks = 0; ks < 2; ++ks)
      qf[f][ks] = *(const b16x8*)(Qb + (size_t)(q0 + wid * 32 + f * 16 + lrow) * 64 +
                                  ks * 32 + (lane >> 4) * 8);

  f32x4 z4 = {0.f, 0.f, 0.f, 0.f};
  f32x4 accO[2][4];
  float m_i[2][4], l_i[2][4];  // l_i is LANE-PARTIAL (reduced at epilogue)
#pragma unroll
  for (int f = 0; f < 2; ++f) {
#pragma unroll
    for (int d = 0; d < 4; ++d) accO[f][d] = z4;
#pragma unroll
    for (int r = 0; r < 4; ++r) { m_i[f][r] = -1e30f; l_i[f][r] = 0.f; }
  }

  short* Pw = Ps + wid * 2048;

  // prologue: stage tile 0 into buffer 0
#pragma unroll
  for (int i = 0; i < 2; ++i) {
    int c = wid * 2 + i;
    gl_lds16(Kb + (size_t)(c * 8 + r8) * 64 + swz8, &Ks[0][c * 512]);
    gl_lds16(Vb + (size_t)(c * 8 + r8) * LL + swz8, &Vs[0][c * 512]);
  }
  asm volatile("s_waitcnt vmcnt(0)" ::: "memory");
  __syncthreads();

  int cur = 0;
  for (int kt = 0; kt < LL / 64; ++kt) {
    // prefetch next K/V tile into the other buffer (lands by end-of-tile)
    if (kt + 1 < LL / 64) {
#pragma unroll
      for (int i = 0; i < 2; ++i) {
        int c = wid * 2 + i;
        gl_lds16(Kb + (size_t)((kt + 1) * 64 + c * 8 + r8) * 64 + swz8,
                 &Ks[cur ^ 1][c * 512]);
        gl_lds16(Vb + (size_t)(c * 8 + r8) * LL + (kt + 1) * 64 + swz8,
                 &Vs[cur ^ 1][c * 512]);
      }
    }

    // S = Q K^T  (Q pre-scaled by 0.125*log2e -> exp2 domain)
    f32x4 sacc[2][4];
#pragma unroll
    for (int f = 0; f < 2; ++f)
#pragma unroll
      for (int kf = 0; kf < 4; ++kf) sacc[f][kf] = z4;

#pragma unroll
    for (int kf = 0; kf < 4; ++kf) {
      int key = kf * 16 + lrow;
      int sw = (key & 7) << 4;
#pragma unroll
      for (int ks = 0; ks < 2; ++ks) {
        b16x8 kfr = *(const b16x8*)(&Ks[cur][0] + key * 64 + (((ks * 64 + hi16) ^ sw) >> 1));
#pragma unroll
        for (int f = 0; f < 2; ++f)
          sacc[f][kf] =
              __builtin_amdgcn_mfma_f32_16x16x32_bf16(qf[f][ks], kfr, sacc[f][kf], 0, 0, 0);
      }
    }

    // ---- defer-max online softmax ----
    float lm[2][4];
    float w = -1e30f;
#pragma unroll
    for (int f = 0; f < 2; ++f)
#pragma unroll
      for (int r = 0; r < 4; ++r) {
        lm[f][r] = fmaxf(fmaxf(sacc[f][0][r], sacc[f][1][r]),
                         fmaxf(sacc[f][2][r], sacc[f][3][r]));
        w = fmaxf(w, lm[f][r] - m_i[f][r]);
      }

    if (!__all(w <= 8.0f)) {
      // rare path: full max-reduce + rescale
#pragma unroll
      for (int f = 0; f < 2; ++f)
#pragma unroll
        for (int r = 0; r < 4; ++r) {
          float mx = lm[f][r];
          mx = fmaxf(mx, __shfl_xor(mx, 1));
          mx = fmaxf(mx, __shfl_xor(mx, 2));
          mx = fmaxf(mx, __shfl_xor(mx, 4));
          mx = fmaxf(mx, __shfl_xor(mx, 8));
          float mnew = fmaxf(m_i[f][r], mx);
          float corr = __builtin_amdgcn_exp2f(m_i[f][r] - mnew);
          l_i[f][r] *= corr;
          m_i[f][r] = mnew;
#pragma unroll
          for (int d = 0; d < 4; ++d) accO[f][d] *= corr;
        }
    }

    // P = exp2(S - m), store swizzled; accumulate lane-partial l
#pragma unroll
    for (int f = 0; f < 2; ++f)
#pragma unroll
      for (int r = 0; r < 4; ++r) {
        int q32 = f * 16 + rbase + r;
        int swq = (q32 & 7) << 4;
        float ps = 0.f;
#pragma unroll
        for (int kf = 0; kf < 4; ++kf) {
          float p = __builtin_amdgcn_exp2f(sacc[f][kf][r] - m_i[f][r]);
          ps += p;
          int key = kf * 16 + lrow;
          Pw[q32 * 64 + (((key * 2) ^ swq) >> 1)] = f2bf(p);
        }
        l_i[f][r] += ps;
      }

    asm volatile("s_waitcnt lgkmcnt(0)" ::: "memory");

    // O += P V
    b16x8 pfr[2][2], vfr[4][2];
#pragma unroll
    for (int f = 0; f < 2; ++f)
#pragma unroll
      for (int ks = 0; ks < 2; ++ks) {
        int q32 = f * 16 + lrow;
        pfr[f][ks] = *(const b16x8*)(Pw + q32 * 64 +
                                     (((ks * 64 + hi16) ^ ((q32 & 7) << 4)) >> 1));
      }
#pragma unroll
    for (int d = 0; d < 4; ++d)
#pragma unroll
      for (int ks = 0; ks < 2; ++ks) {
        int dd = d * 16 + lrow;
        vfr[d][ks] = *(const b16x8*)(&Vs[cur][0] + dd * 64 +
                                     (((ks * 64 + hi16) ^ ((dd & 7) << 4)) >> 1));
      }
#pragma unroll
    for (int f = 0; f < 2; ++f)
#pragma unroll
      for (int d = 0; d < 4; ++d)
#pragma unroll
        for (int ks = 0; ks < 2; ++ks)
          accO[f][d] =
              __builtin_amdgcn_mfma_f32_16x16x32_bf16(pfr[f][ks], vfr[d][ks], accO[f][d], 0, 0, 0);

    // make sure next tile's prefetch has landed, then flip buffers
    asm volatile("s_waitcnt vmcnt(0)" ::: "memory");
    __syncthreads();
    cur ^= 1;
  }

  // epilogue: reduce lane-partial l, O /= l, write to (B, L, H*DK) bf16
  const int bb = bh >> 4, h = bh & 15;
#pragma unroll
  for (int f = 0; f < 2; ++f)
#pragma unroll
    for (int r = 0; r < 4; ++r) {
      float l = l_i[f][r];
      l += __shfl_xor(l, 1);
      l += __shfl_xor(l, 2);
      l += __shfl_xor(l, 4);
      l += __shfl_xor(l, 8);
      float rl = 1.0f / l;
      int q = q0 + wid * 32 + f * 16 + rbase + r;
#pragma unroll
      for (int d = 0; d < 4; ++d) {
        int col = h * 64 + d * 16 + lrow;
        Og[(size_t)(bb * LL + q) * DD + col] = f2bf(accO[f][d][r] * rl);
      }
    }
}

// ---------------- output GEMM: attn[4096,1024] @ WOt + bO -> f32 ----------
__global__ __launch_bounds__(256) void out_gemm(const short* __restrict__ Ab,
                                                const short* __restrict__ Wt,
                                                const float* __restrict__ bO,
                                                float* __restrict__ Out) {
  __shared__ __align__(16) short As[128 * 32];
  __shared__ __align__(16) short Bs[128 * 32];

  const int tid = threadIdx.x;
  const int lane = tid & 63;
  const int wid = tid >> 6;
  const int m0 = blockIdx.y * 128;
  const int n0 = blockIdx.x * 128;

  const int wrow = wid >> 1, wcol = wid & 1;
  const int lrow = lane & 15;
  const int lk8 = (lane >> 4) * 8;
  const int srow = lane >> 2;
  const int scol = (lane & 3) * 8;

  f32x4 z4 = {0.f, 0.f, 0.f, 0.f};
  f32x4 acc[4][4];
#pragma unroll
  for (int i = 0; i < 4; ++i)
#pragma unroll
    for (int j = 0; j < 4; ++j) acc[i][j] = z4;

  for (int kt = 0; kt < DD; kt += 32) {
#pragma unroll
    for (int i = 0; i < 2; ++i) {
      int c = wid * 2 + i;
      gl_lds16(Ab + (size_t)(m0 + c * 16 + srow) * DD + kt + scol, As + c * 512);
      gl_lds16(Wt + (size_t)(n0 + c * 16 + srow) * DD + kt + scol, Bs + c * 512);
    }
    __syncthreads();
    b16x8 a[4], b[4];
#pragma unroll
    for (int i = 0; i < 4; ++i)
      a[i] = *(const b16x8*)(As + (wrow * 64 + i * 16 + lrow) * 32 + lk8);
#pragma unroll
    for (int j = 0; j < 4; ++j)
      b[j] = *(const b16x8*)(Bs + (wcol * 64 + j * 16 + lrow) * 32 + lk8);
#pragma unroll
    for (int i = 0; i < 4; ++i)
#pragma unroll
      for (int j = 0; j < 4; ++j)
        acc[i][j] = __builtin_amdgcn_mfma_f32_16x16x32_bf16(a[i], b[j], acc[i][j], 0, 0, 0);
    __syncthreads();
  }

  float bv[4];
#pragma unroll
  for (int j = 0; j < 4; ++j) bv[j] = bO[n0 + wcol * 64 + j * 16 + lrow];

  const int rbase = (lane >> 4) * 4;
#pragma unroll
  for (int i = 0; i < 4; ++i) {
    int gm = m0 + wrow * 64 + i * 16 + rbase;
#pragma unroll
    for (int j = 0; j < 4; ++j) {
      int gn = n0 + wcol * 64 + j * 16 + lrow;
#pragma unroll
      for (int r = 0; r < 4; ++r)
        Out[(size_t)(gm + r) * DD + gn] = acc[i][j][r] + bv[j];
    }
  }
}

extern "C" void kernel_launch(void* const* d_in, const int* in_sizes, int n_in,
                              void* d_out, int out_size, void* d_ws, size_t ws_size,
                              hipStream_t stream) {
  const float* X = (const float*)d_in[0];
  const float* WQ = (const float*)d_in[1];
  const float* bQ = (const float*)d_in[2];
  const float* WK = (const float*)d_in[3];
  const float* bK = (const float*)d_in[4];
  const float* WV = (const float*)d_in[5];
  const float* bV = (const float*)d_in[6];
  const float* WO = (const float*)d_in[7];
  const float* bO = (const float*)d_in[8];
  float* Out = (float*)d_out;

  // workspace layout (shorts): Xb 4M | Wt 4x1M | Q 4M | K 4M | Vt 4M | At 4M
  if (ws_size < (size_t)24 * 1024 * 1024 * 2) return;
  short* ws = (short*)d_ws;
  short* Xb = ws;
  short* Wt = Xb + (size_t)4096 * 1024;
  short* Qb = Wt + (size_t)4 * 1024 * 1024;
  short* Kb = Qb + (size_t)4096 * 1024;
  short* Vtb = Kb + (size_t)4096 * 1024;
  short* At = Vtb + (size_t)4096 * 1024;

  hipLaunchKernelGGL(xcvt, dim3(4096), dim3(256), 0, stream, X, Xb);
  hipLaunchKernelGGL(wtrans, dim3(32, 32, 4), dim3(256), 0, stream, WQ, WK, WV, WO, Wt);
  hipLaunchKernelGGL(qkv_gemm, dim3(24, 32), dim3(256), 0, stream, Xb, Wt, bQ, bK, bV,
                     Qb, Kb, Vtb);
  hipLaunchKernelGGL(attn, dim3(16, 32), dim3(256), 0, stream, Qb, Kb, Vtb, At);
  hipLaunchKernelGGL(out_gemm, dim3(8, 32), dim3(256), 0, stream, At,
                     Wt + (size_t)3 * 1024 * 1024, bO, Out);
}